// Round 3
// baseline (424.102 us; speedup 1.0000x reference)
//
#include <hip/hip_runtime.h>

// All tensors float32. ws poisoned each iteration; layout below ~20 MB.
// ws layout (float offsets):
#define OFF_SPP   0         // sp partials: [c<16][t<12][col<256]      (49152)
#define OFF_TPH   49152     // tp hidden (post-relu), 256
#define OFF_P1    65536     // fc1 partials: [(t*2048+col)*32+p]       (131072)
#define OFF_P2    196608    // fc2 partials: [(t*2048+col)*16+p]       (65536)
#define OFF_P3    262144    // fc3 partials: [(t*12288+col)*4+p]       (98304)
#define OFF_U     1703936   // U final [ap][n][t] (36864)
#define OFF_E     1777664   // softmax-exp probs [pair<512][6][1024]   (3145728)
#define OFF_IS    4923392   // invS [pair<512][6]                      (3072)

// ---------------------------------------------------------------------------
// 2-row GEMM body, split-K, plain partial stores. Input is either direct
// (PIN==0), a gather from obs (GATHER==1), or the sum of PIN partials.
template<int KS, int PIN, int P, int GATHER>
__device__ __forceinline__ void gemm_body(
    const float* __restrict__ xin, const float* __restrict__ bias_in,
    const float* __restrict__ W, float* __restrict__ part,
    int N, int K, int bx, int by, float* lx, float* red)
{
  int tid = threadIdx.x;
  int k0 = by * KS;
  for (int i = tid; i < 2*KS; i += 256) {
    int t = i / KS, kk = i - t*KS;
    float v;
    if (GATHER) {
      int k = k0 + kk;                      // col of (12 x 8192) obs matrix
      v = xin[(k >> 3)*96 + (k & 7)*12 + 9 + t];  // rows t=9,10 only
    } else if (PIN == 0) {
      v = xin[t*K + k0 + kk];
    } else {
      v = 0.f;
      const float* p0 = xin + (size_t)(t*K + k0 + kk)*PIN;
      #pragma unroll
      for (int pp = 0; pp < PIN; ++pp) v += p0[pp];
    }
    if (bias_in) { v += bias_in[k0 + kk]; v = v > 0.f ? v : 0.f; }
    lx[i] = v;
  }
  __syncthreads();
  int kg = tid >> 5, cg2 = tid & 31;
  int colbase = bx*128 + cg2*4;
  float a0=0,a1=0,a2=0,a3=0,c0=0,c1=0,c2=0,c3=0;
  const int ksub = KS/8;
  for (int kk = kg*ksub; kk < kg*ksub + ksub; ++kk) {
    float4 w = *(const float4*)(W + (size_t)(k0+kk)*N + colbase);
    float x0 = lx[kk], x1 = lx[KS + kk];
    a0=fmaf(x0,w.x,a0); a1=fmaf(x0,w.y,a1); a2=fmaf(x0,w.z,a2); a3=fmaf(x0,w.w,a3);
    c0=fmaf(x1,w.x,c0); c1=fmaf(x1,w.y,c1); c2=fmaf(x1,w.z,c2); c3=fmaf(x1,w.w,c3);
  }
  float* rp = red + (kg*32 + cg2)*8;
  rp[0]=a0; rp[1]=a1; rp[2]=a2; rp[3]=a3; rp[4]=c0; rp[5]=c1; rp[6]=c2; rp[7]=c3;
  __syncthreads();
  int cg3 = tid & 31, q = tid >> 5;
  float s = 0.f;
  #pragma unroll
  for (int g = 0; g < 8; ++g) s += red[(g*32 + cg3)*8 + q];
  int t = q >> 2, c = q & 3;
  part[(size_t)(t*N + bx*128 + cg3*4 + c)*P + by] = s;
}

// ---------------------------------------------------------------------------
// k_front: blocks 0..511 = fc1 GEMM (16 col x 32 k-chunks of 256, obs gathered
// in staging); blocks 512..527 = sp first-layer partials + zero out[1..3];
// block 528 = tp hidden.
__global__ void __launch_bounds__(256) k_front(
    const float* __restrict__ obs, const float* __restrict__ fc_w1,
    float* __restrict__ part1,
    const float* __restrict__ li, const float* __restrict__ gs_w1,
    const float* __restrict__ tf, const float* __restrict__ gt_w1,
    const float* __restrict__ gt_b1,
    float* __restrict__ sp_part, float* __restrict__ tp_h,
    float* __restrict__ out_tail)
{
  __shared__ float smem[2560];   // fc1: lx(512)+red(2048); sp: lil(1536)
  int b = blockIdx.x, tid = threadIdx.x;
  if (b < 512) {
    gemm_body<256, 0, 32, 1>(obs, (const float*)nullptr, fc_w1, part1,
                             2048, 8192, b & 15, b >> 4, smem, smem + 512);
  } else if (b < 528) {
    float (*lil)[128] = (float(*)[128])smem;
    int sb = b - 512;
    int cb = sb & 1, kc = sb >> 1;          // col chunk (128), k chunk (128)
    for (int i = tid; i < 1536; i += 256) {
      int r = i >> 7, kk = i & 127;
      lil[r][kk] = li[r*1024 + kc*128 + kk];
    }
    __syncthreads();
    int col = cb*128 + (tid & 127);
    int kh = tid >> 7;                      // k-half of 64
    float acc[12];
    #pragma unroll
    for (int t=0;t<12;++t) acc[t]=0.f;
    for (int kk = kh*64; kk < kh*64 + 64; ++kk) {
      float w = gs_w1[(size_t)(kc*128 + kk)*256 + col];
      #pragma unroll
      for (int t=0;t<12;++t) acc[t] = fmaf(lil[t][kk], w, acc[t]);
    }
    int c = kc*2 + kh;                      // 0..15 partial chunk
    #pragma unroll
    for (int t=0;t<12;++t) sp_part[(c*12 + t)*256 + col] = acc[t];
    // zero-duty: outputs 1..3 (36864 floats / 16 blocks)
    for (int i = tid; i < 2304; i += 256) out_tail[sb*2304 + i] = 0.f;
  } else {
    float acc = 0.f;
    for (int k = 0; k < 36; ++k)
      acc = fmaf(tf[k], gt_w1[k*256 + tid], acc);
    float v = acc + gt_b1[tid];
    tp_h[tid] = v > 0.f ? v : 0.f;
  }
}

// ---------------------------------------------------------------------------
// k_umid: blocks 0..255 = fc2 GEMM (16 col x 16 k-chunks of 128);
// blocks 256..383 = full-K U kernel: 8 nodes/block, 32 lanes/node, one lane
// per output element (36 sp-type + 3 tp-type, dual-duty lanes 0..6), K=256
// serial. Writes FINAL U (bias+relu+sum) — no partials, no finalize pass.
__global__ void __launch_bounds__(256) k_umid(
    const float* __restrict__ part1, const float* __restrict__ fc_b1,
    const float* __restrict__ fc_w2, float* __restrict__ part2,
    const float* __restrict__ sp_part, const float* __restrict__ gs_b1,
    const float* __restrict__ tp_h,
    const float* __restrict__ gs_w2, const float* __restrict__ gt_w2,
    const float* __restrict__ gs_b2, const float* __restrict__ gt_b2,
    float* __restrict__ U)
{
  __shared__ float smem[3328];  // fc2: lx(256)+red(2048); U: spl(3072)+tpl(256)
  int b = blockIdx.x, tid = threadIdx.x;
  if (b < 256) {
    gemm_body<128, 32, 16, 0>(part1, fc_b1, fc_w2, part2, 2048, 2048,
                              b & 15, b >> 4, smem, smem + 256);
    return;
  }
  float* spl = smem;          // [k<256][t<12] relu'd sp hidden
  float* tpl = smem + 3072;   // [k<256]
  for (int i = tid; i < 3072; i += 256) {
    int k = i / 12, t = i - k*12;
    float v = gs_b1[k];
    #pragma unroll
    for (int c = 0; c < 16; ++c) v += sp_part[(c*12 + t)*256 + k];
    spl[i] = v > 0.f ? v : 0.f;
  }
  tpl[tid] = tp_h[tid];
  __syncthreads();
  int grp = tid >> 5, l = tid & 31;
  int n = (b - 256)*8 + grp;
  // output o1 = l: (ap1, t1); dual output o2 = 32+l for l<7:
  //   l<4 -> sp-type (ap=2, t=8+l);  l in 4..6 -> tp-type ap=l-4
  int ap1 = l / 12, t1 = l - ap1*12;
  bool has2 = (l < 7), sp2 = (l < 4);
  int t2 = 8 + l;
  const float* g1 = gs_w2 + 12*n + 9 + ap1;
  const float* g2 = sp2 ? (gs_w2 + 12*n + 11)
                        : (has2 ? (gt_w2 + 12*n + 9 + (l - 4)) : gs_w2);
  float a1 = 0.f, a2 = 0.f;
  #pragma unroll 8
  for (int k = 0; k < 256; ++k) {
    float w1 = g1[(size_t)k*12288];
    a1 = fmaf(spl[k*12 + t1], w1, a1);
    if (has2) {
      float w2 = g2[(size_t)k*12288];
      float x2 = sp2 ? spl[k*12 + t2] : tpl[k];
      a2 = fmaf(x2, w2, a2);
    }
  }
  float tp0 = __shfl(a2, 4, 32);
  float tp1 = __shfl(a2, 5, 32);
  float tp2 = __shfl(a2, 6, 32);
  float tpv = (ap1 == 0) ? tp0 : ((ap1 == 1) ? tp1 : tp2);
  int c1 = n*12 + 9 + ap1;
  float sv = a1 + gs_b2[c1]; sv = sv > 0.f ? sv : 0.f;
  float tv = tpv + gt_b2[c1]; tv = tv > 0.f ? tv : 0.f;
  U[ap1*12288 + n*12 + t1] = sv + tv;
  if (sp2) {
    int c2 = n*12 + 11;
    float sv2 = a2 + gs_b2[c2]; sv2 = sv2 > 0.f ? sv2 : 0.f;
    float tv2 = tp2 + gt_b2[c2]; tv2 = tv2 > 0.f ? tv2 : 0.f;
    U[2*12288 + n*12 + t2] = sv2 + tv2;
  }
}

// ---------------------------------------------------------------------------
// k_sfc3: blocks 0..383 = fc3 GEMM (96 col x 4 k-chunks of 512);
// blocks 384..511 = scores (4 pairs each): P from U, scores over U10,
// threshold, softmax -> E (exp probs) + invS to global. Runs concurrently
// with fc3 (scores need only U, ready after k_umid).
#define SS 1032
__global__ void __launch_bounds__(256) k_sfc3(
    const float* __restrict__ part2, const float* __restrict__ fc_b2,
    const float* __restrict__ fc_w3, float* __restrict__ part3,
    const float* __restrict__ U, const float* __restrict__ Bm,
    float* __restrict__ E, float* __restrict__ invSg)
{
  __shared__ float smem[6448];  // gemm: lx(1024)+red(2048); scores: sc+Pm+Bl
  int b = blockIdx.x, tid = threadIdx.x;
  if (b < 384) {
    gemm_body<512, 16, 4, 0>(part2, fc_b2, fc_w3, part3, 12288, 2048,
                             b >> 2, b & 3, smem, smem + 1024);
    return;
  }
  float* sc = smem;            // 6*1032
  float* Pm = smem + 6192;     // [2][3][12]
  float* Bl = smem + 6264;     // 144
  int sb = b - 384;            // 0..127
  if (tid < 144) Bl[tid] = Bm[tid];
  __syncthreads();
  const float* U10 = U + 12288;
  for (int pp = 0; pp < 4; ++pp) {
    int pair = sb*4 + pp;
    int i0 = pair*2;
    if (tid < 72) {
      int r = tid / 36, ap = (tid / 12) % 3, j = tid % 12;
      float s = 0.f;
      #pragma unroll
      for (int t=0;t<12;++t)
        s = fmaf(U[ap*12288 + (i0+r)*12 + t], Bl[t*12 + j], s);
      Pm[(r*3+ap)*12 + j] = s;
    }
    __syncthreads();
    for (int jj = 0; jj < 4; ++jj) {
      int j = tid + jj*256;
      const float4* ur = (const float4*)(U10 + j*12);
      float4 u0 = ur[0], u1 = ur[1], u2 = ur[2];
      float u[12] = {u0.x,u0.y,u0.z,u0.w,u1.x,u1.y,u1.z,u1.w,u2.x,u2.y,u2.z,u2.w};
      #pragma unroll
      for (int r=0;r<2;++r)
        #pragma unroll
        for (int ap=0;ap<3;++ap) {
          float s = 0.f;
          #pragma unroll
          for (int t=0;t<12;++t) s = fmaf(Pm[(r*3+ap)*12 + t], u[t], s);
          sc[(r*3+ap)*SS + j] = (s >= 0.05f) ? s : 0.f;
        }
    }
    __syncthreads();
    int wv = tid >> 6, ln = tid & 63;
    for (int pr = wv; pr < 6; pr += 4) {
      float m = -1e30f;
      for (int q = 0; q < 16; ++q) m = fmaxf(m, sc[pr*SS + ln + q*64]);
      #pragma unroll
      for (int o = 32; o > 0; o >>= 1) m = fmaxf(m, __shfl_xor(m, o));
      float sum = 0.f;
      for (int q = 0; q < 16; ++q) {
        int j = ln + q*64;
        float e = __expf(sc[pr*SS + j] - m);
        E[(size_t)pair*6144 + pr*1024 + j] = e;
        sum += e;
      }
      #pragma unroll
      for (int o = 32; o > 0; o >>= 1) sum += __shfl_xor(sum, o);
      if (ln == 0) invSg[pair*6 + pr] = 1.f / sum;
    }
    __syncthreads();
  }
}

// ---------------------------------------------------------------------------
// k_out: 512 pair-blocks. Weighted X-sums (Y folded via linearity:
// sum_j e_j * (relu(X_j) @ Ws) = (sum_j e_j relu(X_j)) @ Ws), X recomputed
// from part3 (4-partial sum + bias + relu) on the fly; 12x12 Ws multiply
// + softmax-normalize + epilogue at the end.
__global__ void __launch_bounds__(256) k_out(
    const float* __restrict__ E, const float* __restrict__ invSg,
    const float* __restrict__ part3, const float* __restrict__ fc_b3,
    const float* __restrict__ Wf, const float* __restrict__ Wb,
    const float* __restrict__ bvec, float* __restrict__ out)
{
  __shared__ float red[4608];
  __shared__ float Ws0[144], Ws1[144], Ws2[144];
  __shared__ float wbuf[72];
  __shared__ float invS[6], bl[12];
  int b = blockIdx.x, tid = threadIdx.x;
  if (tid < 144) {
    Ws0[tid] = Wf[144 + tid];          // Wf[1]       (path 0, L(9,10))
    Ws1[tid] = Wf[tid] + Wb[tid];      // Wf[0]+Wb[0] (path 1, L(10,10))
    Ws2[tid] = Wb[144 + tid];          // Wb[1]       (path 2, L(11,10))
  }
  if (tid < 6)  invS[tid] = invSg[b*6 + tid];
  if (tid < 12) bl[tid]   = bvec[tid];
  float acc[2][12];
  #pragma unroll
  for (int r=0;r<2;++r)
    #pragma unroll
    for (int f=0;f<12;++f) acc[r][f] = 0.f;
  int q3 = tid >> 6, jg = tid & 63;
  if (tid < 192) {
    const float* Eb = E + (size_t)b*6144;
    int row = (q3 == 1) ? 1 : 0;       // paths 0,2 use X9 (row 0); path 1 X10
    const float* p3r = part3 + (size_t)row*49152;
    for (int q = 0; q < 16; ++q) {
      int j = jg + q*64;
      float e0 = Eb[q3*1024 + j];
      float e1 = Eb[(3 + q3)*1024 + j];
      const float4* px = (const float4*)(p3r + (size_t)j*48);
      const float* bb = fc_b3 + j*12;
      #pragma unroll
      for (int f = 0; f < 12; ++f) {
        float4 v4 = px[f];
        float x = v4.x + v4.y + v4.z + v4.w + bb[f];
        x = x > 0.f ? x : 0.f;
        acc[0][f] = fmaf(e0, x, acc[0][f]);
        acc[1][f] = fmaf(e1, x, acc[1][f]);
      }
    }
  }
  if (tid < 192) {
    #pragma unroll
    for (int r=0;r<2;++r)
      #pragma unroll
      for (int f=0;f<12;++f)
        red[((q3*2 + r)*12 + f)*64 + jg] = acc[r][f];
  }
  __syncthreads();
  if (tid < 72) {
    int q3b = tid / 24, rr = (tid / 12) % 2, f = tid % 12;
    float s = 0.f;
    for (int g = 0; g < 64; ++g) s += red[((q3b*2 + rr)*12 + f)*64 + g];
    wbuf[(q3b*2 + rr)*12 + f] = s;
  }
  __syncthreads();
  if (tid < 24) {
    int r = tid / 12, g = tid % 12;
    float y0=0.f, y1=0.f, y2=0.f;
    #pragma unroll
    for (int f=0; f<12; ++f) {
      y0 = fmaf(wbuf[(0*2+r)*12+f], Ws0[f*12+g], y0);
      y1 = fmaf(wbuf[(1*2+r)*12+f], Ws1[f*12+g], y1);
      y2 = fmaf(wbuf[(2*2+r)*12+f], Ws2[f*12+g], y2);
    }
    float a1v = invS[r*3+1]*y1;
    float a2v = invS[r*3+0]*y0 + invS[r*3+2]*y2;
    float v1 = a1v + bl[g]; v1 = v1>0.f ? v1 : 0.f;
    float v2 = a2v + bl[g]; v2 = v2>0.f ? v2 : 0.f;
    out[(b*2+r)*12 + g] = v1 + v2;
  }
}

extern "C" void kernel_launch(void* const* d_in, const int* in_sizes, int n_in,
                              void* d_out, int out_size, void* d_ws, size_t ws_size,
                              hipStream_t stream)
{
  const float* obs   = (const float*)d_in[0];
  const float* tf    = (const float*)d_in[1];
  const float* fc_w1 = (const float*)d_in[2];
  const float* fc_b1 = (const float*)d_in[3];
  const float* fc_w2 = (const float*)d_in[4];
  const float* fc_b2 = (const float*)d_in[5];
  const float* fc_w3 = (const float*)d_in[6];
  const float* fc_b3 = (const float*)d_in[7];
  const float* Wf    = (const float*)d_in[8];
  const float* Wb    = (const float*)d_in[9];
  const float* bvec  = (const float*)d_in[10];
  const float* li    = (const float*)d_in[11];
  const float* gs_w1 = (const float*)d_in[12];
  const float* gs_b1 = (const float*)d_in[13];
  const float* gs_w2 = (const float*)d_in[14];
  const float* gs_b2 = (const float*)d_in[15];
  const float* gt_w1 = (const float*)d_in[16];
  const float* gt_b1 = (const float*)d_in[17];
  const float* gt_w2 = (const float*)d_in[18];
  const float* gt_b2 = (const float*)d_in[19];
  const float* Bm    = (const float*)d_in[20];
  float* out = (float*)d_out;
  float* ws  = (float*)d_ws;

  float* sp_part = ws + OFF_SPP;
  float* tp_h    = ws + OFF_TPH;
  float* part1   = ws + OFF_P1;
  float* part2   = ws + OFF_P2;
  float* part3   = ws + OFF_P3;
  float* U       = ws + OFF_U;
  float* E       = ws + OFF_E;
  float* invSg   = ws + OFF_IS;

  // fc1 (512, split-K 32x256, obs gathered in staging) + sp/zero (16) + tp (1)
  k_front<<<dim3(529), dim3(256), 0, stream>>>(obs, fc_w1, part1,
                                               li, gs_w1, tf, gt_w1, gt_b1,
                                               sp_part, tp_h, out + 12288);
  // fc2 (256, split-K 16x128) || full-K U (128) -> final U
  k_umid<<<dim3(384), dim3(256), 0, stream>>>(part1, fc_b1, fc_w2, part2,
                                              sp_part, gs_b1, tp_h,
                                              gs_w2, gt_w2, gs_b2, gt_b2, U);
  // fc3 (384, split-K 4x512) || scores+softmax (128 blocks x 4 pairs) -> E,invS
  k_sfc3<<<dim3(512), dim3(256), 0, stream>>>(part2, fc_b2, fc_w3, part3,
                                              U, Bm, E, invSg);
  // weighted X-sums + 12x12 Ws + epilogue
  k_out<<<dim3(512), dim3(256), 0, stream>>>(E, invSg, part3, fc_b3,
                                             Wf, Wb, bvec, out);
}

// Round 4
// 305.388 us; speedup vs baseline: 1.3887x; 1.3887x over previous
//
#include <hip/hip_runtime.h>

// All tensors float32. ws poisoned each iteration; layout below ~7 MB.
// ws layout (float offsets):
#define OFF_SPP   0         // sp partials: [c<16][t<12][col<256]      (49152)
#define OFF_TPH   49152     // tp hidden (post-relu), 256
#define OFF_P1    65536     // fc1 partials: [(t*2048+col)*32+p]       (131072)
#define OFF_P2    196608    // fc2 partials: [(t*2048+col)*16+p]       (65536)
#define OFF_P3    262144    // fc3 partials: [(t*12288+col)*4+p]       (98304)
#define OFF_UP    393216    // U partials:  [y<32][ap<3][n<1024][t<12] (1179648)
#define OFF_TPP   1572864   // tp2 partials:[y<32][n<1024][ap<3]       (98304)
#define OFF_U     1703936   // U final [ap][n][t] (36864)

// ---------------------------------------------------------------------------
// 2-row GEMM body, split-K, plain partial stores. Input is either direct
// (PIN==0), a gather from obs (GATHER==1), or the sum of PIN partials.
template<int KS, int PIN, int P, int GATHER>
__device__ __forceinline__ void gemm_body(
    const float* __restrict__ xin, const float* __restrict__ bias_in,
    const float* __restrict__ W, float* __restrict__ part,
    int N, int K, int bx, int by, float* lx, float* red)
{
  int tid = threadIdx.x;
  int k0 = by * KS;
  for (int i = tid; i < 2*KS; i += 256) {
    int t = i / KS, kk = i - t*KS;
    float v;
    if (GATHER) {
      int k = k0 + kk;                      // col of (12 x 8192) obs matrix
      v = xin[(k >> 3)*96 + (k & 7)*12 + 9 + t];  // rows t=9,10 only
    } else if (PIN == 0) {
      v = xin[t*K + k0 + kk];
    } else {
      v = 0.f;
      const float* p0 = xin + (size_t)(t*K + k0 + kk)*PIN;
      #pragma unroll
      for (int pp = 0; pp < PIN; ++pp) v += p0[pp];
    }
    if (bias_in) { v += bias_in[k0 + kk]; v = v > 0.f ? v : 0.f; }
    lx[i] = v;
  }
  __syncthreads();
  int kg = tid >> 5, cg2 = tid & 31;
  int colbase = bx*128 + cg2*4;
  float a0=0,a1=0,a2=0,a3=0,c0=0,c1=0,c2=0,c3=0;
  const int ksub = KS/8;
  for (int kk = kg*ksub; kk < kg*ksub + ksub; ++kk) {
    float4 w = *(const float4*)(W + (size_t)(k0+kk)*N + colbase);
    float x0 = lx[kk], x1 = lx[KS + kk];
    a0=fmaf(x0,w.x,a0); a1=fmaf(x0,w.y,a1); a2=fmaf(x0,w.z,a2); a3=fmaf(x0,w.w,a3);
    c0=fmaf(x1,w.x,c0); c1=fmaf(x1,w.y,c1); c2=fmaf(x1,w.z,c2); c3=fmaf(x1,w.w,c3);
  }
  float* rp = red + (kg*32 + cg2)*8;
  rp[0]=a0; rp[1]=a1; rp[2]=a2; rp[3]=a3; rp[4]=c0; rp[5]=c1; rp[6]=c2; rp[7]=c3;
  __syncthreads();
  int cg3 = tid & 31, q = tid >> 5;
  float s = 0.f;
  #pragma unroll
  for (int g = 0; g < 8; ++g) s += red[(g*32 + cg3)*8 + q];
  int t = q >> 2, c = q & 3;
  part[(size_t)(t*N + bx*128 + cg3*4 + c)*P + by] = s;
}

// ---------------------------------------------------------------------------
// k_front: blocks 0..511 = fc1 GEMM (16 col x 32 k-chunks of 256, obs gathered
// in staging); blocks 512..527 = sp first-layer partials + zero out[1..3];
// block 528 = tp hidden.
__global__ void __launch_bounds__(256) k_front(
    const float* __restrict__ obs, const float* __restrict__ fc_w1,
    float* __restrict__ part1,
    const float* __restrict__ li, const float* __restrict__ gs_w1,
    const float* __restrict__ tf, const float* __restrict__ gt_w1,
    const float* __restrict__ gt_b1,
    float* __restrict__ sp_part, float* __restrict__ tp_h,
    float* __restrict__ out_tail)
{
  __shared__ float smem[2560];   // fc1: lx(512)+red(2048); sp: lil(1536)
  int b = blockIdx.x, tid = threadIdx.x;
  if (b < 512) {
    gemm_body<256, 0, 32, 1>(obs, (const float*)nullptr, fc_w1, part1,
                             2048, 8192, b & 15, b >> 4, smem, smem + 512);
  } else if (b < 528) {
    float (*lil)[128] = (float(*)[128])smem;
    int sb = b - 512;
    int cb = sb & 1, kc = sb >> 1;          // col chunk (128), k chunk (128)
    for (int i = tid; i < 1536; i += 256) {
      int r = i >> 7, kk = i & 127;
      lil[r][kk] = li[r*1024 + kc*128 + kk];
    }
    __syncthreads();
    int col = cb*128 + (tid & 127);
    int kh = tid >> 7;                      // k-half of 64
    float acc[12];
    #pragma unroll
    for (int t=0;t<12;++t) acc[t]=0.f;
    for (int kk = kh*64; kk < kh*64 + 64; ++kk) {
      float w = gs_w1[(size_t)(kc*128 + kk)*256 + col];
      #pragma unroll
      for (int t=0;t<12;++t) acc[t] = fmaf(lil[t][kk], w, acc[t]);
    }
    int c = kc*2 + kh;                      // 0..15 partial chunk
    #pragma unroll
    for (int t=0;t<12;++t) sp_part[(c*12 + t)*256 + col] = acc[t];
    // zero-duty: outputs 1..3 (36864 floats / 16 blocks)
    for (int i = tid; i < 2304; i += 256) out_tail[sb*2304 + i] = 0.f;
  } else {
    float acc = 0.f;
    for (int k = 0; k < 36; ++k)
      acc = fmaf(tf[k], gt_w1[k*256 + tid], acc);
    float v = acc + gt_b1[tid];
    tp_h[tid] = v > 0.f ? v : 0.f;
  }
}

// ---------------------------------------------------------------------------
// k_umid: blocks 0..255 = fc2 GEMM (16 col x 16 k-chunks of 128);
// blocks 256..383 = split-K U-GEMM (4 node-groups x 32 k-chunks of 8),
// partial stores (R1-verified pattern: 8 independent float4 loads per block,
// latency fully overlapped with the BW-bound fc2 blocks).
__global__ void __launch_bounds__(256) k_umid(
    const float* __restrict__ part1, const float* __restrict__ fc_b1,
    const float* __restrict__ fc_w2, float* __restrict__ part2,
    const float* __restrict__ sp_part, const float* __restrict__ gs_b1,
    const float* __restrict__ tp_h,
    const float* __restrict__ gs_w2, const float* __restrict__ gt_w2,
    float* __restrict__ U_part, float* __restrict__ tp_part)
{
  __shared__ float smem[2304];  // fc2: lx(256)+red(2048); U: spl(96)+tpl(8)
  int b = blockIdx.x, tid = threadIdx.x;
  if (b < 256) {
    gemm_body<128, 32, 16, 0>(part1, fc_b1, fc_w2, part2, 2048, 2048,
                              b & 15, b >> 4, smem, smem + 256);
    return;
  }
  float* spl = smem;        // 96: relu'd sp hidden [kk<8][t<12]
  float* tpl = smem + 96;   // 8
  int ug = b - 256;
  int n  = (ug & 3)*256 + tid;
  int uy = ug >> 2;
  int k0 = uy*8;
  if (tid < 96) {
    int kk = tid / 12, t = tid % 12;
    float v = gs_b1[k0 + kk];
    #pragma unroll
    for (int c = 0; c < 16; ++c) v += sp_part[(c*12 + t)*256 + k0 + kk];
    spl[kk*12 + t] = v > 0.f ? v : 0.f;
  }
  if (tid < 8) tpl[tid] = tp_h[k0 + tid];
  __syncthreads();
  float sA[3][12];
  float tA[3] = {0.f, 0.f, 0.f};
  #pragma unroll
  for (int ap=0;ap<3;++ap)
    #pragma unroll
    for (int t=0;t<12;++t) sA[ap][t]=0.f;
  #pragma unroll
  for (int kk = 0; kk < 8; ++kk) {
    float4 ws4 = *(const float4*)(gs_w2 + (size_t)(k0+kk)*12288 + 12*n + 8);
    float4 wt4 = *(const float4*)(gt_w2 + (size_t)(k0+kk)*12288 + 12*n + 8);
    float w0 = ws4.y, w1 = ws4.z, w2 = ws4.w;
    #pragma unroll
    for (int t=0;t<12;++t) {
      float s = spl[kk*12 + t];
      sA[0][t] = fmaf(s, w0, sA[0][t]);
      sA[1][t] = fmaf(s, w1, sA[1][t]);
      sA[2][t] = fmaf(s, w2, sA[2][t]);
    }
    float tv = tpl[kk];
    tA[0] = fmaf(tv, wt4.y, tA[0]);
    tA[1] = fmaf(tv, wt4.z, tA[1]);
    tA[2] = fmaf(tv, wt4.w, tA[2]);
  }
  #pragma unroll
  for (int ap=0;ap<3;++ap) {
    #pragma unroll
    for (int t=0;t<12;++t)
      U_part[(size_t)uy*36864 + ap*12288 + n*12 + t] = sA[ap][t];
    tp_part[uy*3072 + n*3 + ap] = tA[ap];
  }
}

// ---------------------------------------------------------------------------
// k_fc3u: blocks 0..383 = fc3 GEMM (96 col x 4 k-chunks of 512);
// blocks 384..527 = U finalize (sum 32 partials + bias/relu epilogue),
// hidden under fc3's 96 MB weight stream.
__global__ void __launch_bounds__(256) k_fc3u(
    const float* __restrict__ part2, const float* __restrict__ fc_b2,
    const float* __restrict__ fc_w3, float* __restrict__ part3,
    const float* __restrict__ U_part, const float* __restrict__ tp_part,
    const float* __restrict__ gs_b2, const float* __restrict__ gt_b2,
    float* __restrict__ U)
{
  __shared__ float smem[3072];  // gemm: lx(1024)+red(2048)
  int b = blockIdx.x, tid = threadIdx.x;
  if (b < 384) {
    gemm_body<512, 16, 4, 0>(part2, fc_b2, fc_w3, part3, 12288, 2048,
                             b >> 2, b & 3, smem, smem + 1024);
    return;
  }
  int i = (b - 384)*256 + tid;            // < 36864
  float us = 0.f;
  for (int y = 0; y < 32; ++y) us += U_part[(size_t)y*36864 + i];
  int ap = i / 12288, rem = i - ap*12288, n = rem / 12;
  float ts = 0.f;
  for (int y = 0; y < 32; ++y) ts += tp_part[y*3072 + n*3 + ap];
  int c = n*12 + 9 + ap;
  float sv = us + gs_b2[c]; sv = sv > 0.f ? sv : 0.f;
  float tv = ts + gt_b2[c]; tv = tv > 0.f ? tv : 0.f;
  U[i] = sv + tv;
}

// ---------------------------------------------------------------------------
// k_final: fused scores -> threshold -> softmax -> weighted X-sum -> 12x12 Ws
// -> normalize -> epilogue. TWO rows per block; exp values live in LDS only
// (no E round-trip); Y folded via linearity:
// sum_j e_j*(relu(X_j)@Ws) = (sum_j e_j relu(X_j))@Ws, X recomputed from part3.
#define SS 1032
__global__ void __launch_bounds__(256) k_final(
    const float* __restrict__ U, const float* __restrict__ Bm,
    const float* __restrict__ part3, const float* __restrict__ fc_b3,
    const float* __restrict__ Wf, const float* __restrict__ Wb,
    const float* __restrict__ bvec, float* __restrict__ out)
{
  __shared__ float sc[6*SS];     // scores/exp; aliased as red after use
  __shared__ float Pm[72];
  __shared__ float invS[6];
  __shared__ float Bl[144];
  __shared__ float Ws0[144], Ws1[144], Ws2[144];
  __shared__ float wbuf[72];
  __shared__ float bl[12];
  int tid = threadIdx.x;
  int i0 = blockIdx.x*2;
  if (tid < 144) {
    Bl[tid]  = Bm[tid];
    Ws0[tid] = Wf[144 + tid];          // Wf[1]       (path 0, L(9,10))
    Ws1[tid] = Wf[tid] + Wb[tid];      // Wf[0]+Wb[0] (path 1, L(10,10))
    Ws2[tid] = Wb[144 + tid];          // Wb[1]       (path 2, L(11,10))
  }
  if (tid < 12) bl[tid] = bvec[tid];
  __syncthreads();
  if (tid < 72) {
    int r = tid / 36, ap = (tid / 12) % 3, j = tid % 12;
    float s = 0.f;
    #pragma unroll
    for (int t=0;t<12;++t)
      s = fmaf(U[ap*12288 + (i0+r)*12 + t], Bl[t*12 + j], s);
    Pm[(r*3+ap)*12 + j] = s;
  }
  __syncthreads();
  const float* U10 = U + 12288;
  for (int jj = 0; jj < 4; ++jj) {
    int j = tid + jj*256;
    const float4* ur = (const float4*)(U10 + j*12);
    float4 u0 = ur[0], u1 = ur[1], u2 = ur[2];
    float u[12] = {u0.x,u0.y,u0.z,u0.w,u1.x,u1.y,u1.z,u1.w,u2.x,u2.y,u2.z,u2.w};
    #pragma unroll
    for (int r=0;r<2;++r)
      #pragma unroll
      for (int ap=0;ap<3;++ap) {
        float s = 0.f;
        #pragma unroll
        for (int t=0;t<12;++t) s = fmaf(Pm[(r*3+ap)*12 + t], u[t], s);
        sc[(r*3+ap)*SS + j] = (s >= 0.05f) ? s : 0.f;
      }
  }
  __syncthreads();
  int wv = tid >> 6, ln = tid & 63;
  for (int pr = wv; pr < 6; pr += 4) {
    float m = -1e30f;
    for (int q = 0; q < 16; ++q) m = fmaxf(m, sc[pr*SS + ln + q*64]);
    #pragma unroll
    for (int o = 32; o > 0; o >>= 1) m = fmaxf(m, __shfl_xor(m, o));
    float sum = 0.f;
    for (int q = 0; q < 16; ++q) {
      int j = ln + q*64;
      float e = __expf(sc[pr*SS + j] - m);
      sc[pr*SS + j] = e;
      sum += e;
    }
    #pragma unroll
    for (int o = 32; o > 0; o >>= 1) sum += __shfl_xor(sum, o);
    if (ln == 0) invS[pr] = 1.f / sum;
  }
  __syncthreads();
  float acc[2][12];
  #pragma unroll
  for (int r = 0; r < 2; ++r)
    #pragma unroll
    for (int f = 0; f < 12; ++f)
      acc[r][f] = 0.f;
  int q3 = tid >> 6, jg = tid & 63;
  if (tid < 192) {
    int row = (q3 == 1) ? 1 : 0;       // paths 0,2 use X9 (row 0); path 1 X10
    const float* p3r = part3 + (size_t)row*49152;
    for (int q = 0; q < 16; ++q) {
      int j = jg + q*64;
      float e0 = sc[q3*SS + j];          // pr = 0*3+q3
      float e1 = sc[(3 + q3)*SS + j];    // pr = 1*3+q3
      const float4* px = (const float4*)(p3r + (size_t)j*48);
      const float* bb = fc_b3 + j*12;
      #pragma unroll
      for (int f = 0; f < 12; ++f) {
        float4 v4 = px[f];
        float x = v4.x + v4.y + v4.z + v4.w + bb[f];
        x = x > 0.f ? x : 0.f;
        acc[0][f] = fmaf(e0, x, acc[0][f]);
        acc[1][f] = fmaf(e1, x, acc[1][f]);
      }
    }
  }
  __syncthreads();
  float* red = sc;                     // sc values consumed; reuse as scratch
  if (tid < 192) {
    #pragma unroll
    for (int r=0;r<2;++r)
      #pragma unroll
      for (int f=0;f<12;++f)
        red[((q3*2 + r)*12 + f)*64 + jg] = acc[r][f];
  }
  __syncthreads();
  if (tid < 72) {
    int q3b = tid / 24, rr = (tid / 12) % 2, f = tid % 12;
    float s = 0.f;
    for (int g = 0; g < 64; ++g) s += red[((q3b*2 + rr)*12 + f)*64 + g];
    wbuf[(q3b*2 + rr)*12 + f] = s;
  }
  __syncthreads();
  if (tid < 24) {
    int r = tid / 12, g = tid % 12;
    float y0=0.f, y1=0.f, y2=0.f;
    #pragma unroll
    for (int f=0; f<12; ++f) {
      y0 = fmaf(wbuf[(0*2+r)*12+f], Ws0[f*12+g], y0);
      y1 = fmaf(wbuf[(1*2+r)*12+f], Ws1[f*12+g], y1);
      y2 = fmaf(wbuf[(2*2+r)*12+f], Ws2[f*12+g], y2);
    }
    float a1v = invS[r*3+1]*y1;
    float a2v = invS[r*3+0]*y0 + invS[r*3+2]*y2;
    float v1 = a1v + bl[g]; v1 = v1>0.f ? v1 : 0.f;
    float v2 = a2v + bl[g]; v2 = v2>0.f ? v2 : 0.f;
    out[(i0+r)*12 + g] = v1 + v2;
  }
}

extern "C" void kernel_launch(void* const* d_in, const int* in_sizes, int n_in,
                              void* d_out, int out_size, void* d_ws, size_t ws_size,
                              hipStream_t stream)
{
  const float* obs   = (const float*)d_in[0];
  const float* tf    = (const float*)d_in[1];
  const float* fc_w1 = (const float*)d_in[2];
  const float* fc_b1 = (const float*)d_in[3];
  const float* fc_w2 = (const float*)d_in[4];
  const float* fc_b2 = (const float*)d_in[5];
  const float* fc_w3 = (const float*)d_in[6];
  const float* fc_b3 = (const float*)d_in[7];
  const float* Wf    = (const float*)d_in[8];
  const float* Wb    = (const float*)d_in[9];
  const float* bvec  = (const float*)d_in[10];
  const float* li    = (const float*)d_in[11];
  const float* gs_w1 = (const float*)d_in[12];
  const float* gs_b1 = (const float*)d_in[13];
  const float* gs_w2 = (const float*)d_in[14];
  const float* gs_b2 = (const float*)d_in[15];
  const float* gt_w1 = (const float*)d_in[16];
  const float* gt_b1 = (const float*)d_in[17];
  const float* gt_w2 = (const float*)d_in[18];
  const float* gt_b2 = (const float*)d_in[19];
  const float* Bm    = (const float*)d_in[20];
  float* out = (float*)d_out;
  float* ws  = (float*)d_ws;

  float* sp_part = ws + OFF_SPP;
  float* tp_h    = ws + OFF_TPH;
  float* part1   = ws + OFF_P1;
  float* part2   = ws + OFF_P2;
  float* part3   = ws + OFF_P3;
  float* U_part  = ws + OFF_UP;
  float* tp_part = ws + OFF_TPP;
  float* U       = ws + OFF_U;

  // fc1 (512, split-K 32x256, obs gathered in staging) + sp/zero (16) + tp (1)
  k_front<<<dim3(529), dim3(256), 0, stream>>>(obs, fc_w1, part1,
                                               li, gs_w1, tf, gt_w1, gt_b1,
                                               sp_part, tp_h, out + 12288);
  // fc2 (256, split-K 16x128) || split-K U-GEMM (128) -> U_part, tp_part
  k_umid<<<dim3(384), dim3(256), 0, stream>>>(part1, fc_b1, fc_w2, part2,
                                              sp_part, gs_b1, tp_h,
                                              gs_w2, gt_w2, U_part, tp_part);
  // fc3 (384, split-K 4x512) || U finalize (144)
  k_fc3u<<<dim3(528), dim3(256), 0, stream>>>(part2, fc_b2, fc_w3, part3,
                                              U_part, tp_part, gs_b2, gt_b2, U);
  // fused scores/softmax/weighted-sum/epilogue
  k_final<<<dim3(512), dim3(256), 0, stream>>>(U, Bm, part3, fc_b3,
                                               Wf, Wb, bvec, out);
}

// Round 6
// 291.927 us; speedup vs baseline: 1.4528x; 1.0461x over previous
//
#include <hip/hip_runtime.h>

// All tensors float32. ws poisoned each iteration; layout below ~7 MB.
// ws layout (float offsets):
#define OFF_SPP   0         // sp partials: [c<16][t<12][col<256]      (49152)
#define OFF_TPH   49152     // tp hidden (post-relu), 256
#define OFF_P1    65536     // fc1 partials: [(t*2048+col)*64+p]       (262144)
#define OFF_P2    327680    // fc2 partials: [(t*2048+col)*32+p]       (131072)
#define OFF_X     458752    // X_raw [t<2][12288], init fc_b3, atomic  (24576)
#define OFF_UP    524288    // U partials:  [y<32][ap<3][n<1024][t<12] (1179648)
#define OFF_TPP   1703936   // tp2 partials:[y<32][n<1024][ap<3]       (98304)
#define OFF_U     1802240   // U final [ap][n][t] (36864)

// ---------------------------------------------------------------------------
// 2-row GEMM body, split-K. Input is either direct (PIN==0), a gather from
// obs (GATHER==1), or the sum of PIN partials (+bias+relu). Output: plain
// partial store (ATOM==0) or device-scope atomicAdd into a pre-initialized
// accumulator (ATOM==1, P ignored).
template<int KS, int PIN, int P, int GATHER, int ATOM>
__device__ __forceinline__ void gemm_body(
    const float* __restrict__ xin, const float* __restrict__ bias_in,
    const float* __restrict__ W, float* __restrict__ part,
    int N, int K, int bx, int by, float* lx, float* red)
{
  int tid = threadIdx.x;
  int k0 = by * KS;
  for (int i = tid; i < 2*KS; i += 256) {
    int t = i / KS, kk = i - t*KS;
    float v;
    if (GATHER) {
      int k = k0 + kk;                      // col of (12 x 8192) obs matrix
      v = xin[(k >> 3)*96 + (k & 7)*12 + 9 + t];  // rows t=9,10 only
    } else if (PIN == 0) {
      v = xin[t*K + k0 + kk];
    } else {
      v = 0.f;
      const float* p0 = xin + (size_t)(t*K + k0 + kk)*PIN;
      #pragma unroll
      for (int pp = 0; pp < PIN; ++pp) v += p0[pp];
    }
    if (bias_in) { v += bias_in[k0 + kk]; v = v > 0.f ? v : 0.f; }
    lx[i] = v;
  }
  __syncthreads();
  int kg = tid >> 5, cg2 = tid & 31;
  int colbase = bx*128 + cg2*4;
  float a0=0,a1=0,a2=0,a3=0,c0=0,c1=0,c2=0,c3=0;
  const int ksub = KS/8;
  for (int kk = kg*ksub; kk < kg*ksub + ksub; ++kk) {
    float4 w = *(const float4*)(W + (size_t)(k0+kk)*N + colbase);
    float x0 = lx[kk], x1 = lx[KS + kk];
    a0=fmaf(x0,w.x,a0); a1=fmaf(x0,w.y,a1); a2=fmaf(x0,w.z,a2); a3=fmaf(x0,w.w,a3);
    c0=fmaf(x1,w.x,c0); c1=fmaf(x1,w.y,c1); c2=fmaf(x1,w.z,c2); c3=fmaf(x1,w.w,c3);
  }
  float* rp = red + (kg*32 + cg2)*8;
  rp[0]=a0; rp[1]=a1; rp[2]=a2; rp[3]=a3; rp[4]=c0; rp[5]=c1; rp[6]=c2; rp[7]=c3;
  __syncthreads();
  int cg3 = tid & 31, q = tid >> 5;
  float s = 0.f;
  #pragma unroll
  for (int g = 0; g < 8; ++g) s += red[(g*32 + cg3)*8 + q];
  int t = q >> 2, c = q & 3;
  if (ATOM) {
    atomicAdd(part + (size_t)t*N + bx*128 + cg3*4 + c, s);
  } else {
    part[(size_t)(t*N + bx*128 + cg3*4 + c)*P + by] = s;
  }
}

// ---------------------------------------------------------------------------
// k_front: blocks 0..1023 = fc1 GEMM (16 col x 64 k-chunks of 128, obs
// gathered in staging); blocks 1024..1039 = sp first-layer partials + zero
// out[1..3] + init X_raw with fc_b3; block 1040 = tp hidden.
__global__ void __launch_bounds__(256) k_front(
    const float* __restrict__ obs, const float* __restrict__ fc_w1,
    float* __restrict__ part1,
    const float* __restrict__ li, const float* __restrict__ gs_w1,
    const float* __restrict__ tf, const float* __restrict__ gt_w1,
    const float* __restrict__ gt_b1, const float* __restrict__ fc_b3,
    float* __restrict__ sp_part, float* __restrict__ tp_h,
    float* __restrict__ X_raw, float* __restrict__ out_tail)
{
  __shared__ float smem[2304];   // fc1: lx(256)+red(2048); sp: lil(1536)
  int b = blockIdx.x, tid = threadIdx.x;
  if (b < 1024) {
    gemm_body<128, 0, 64, 1, 0>(obs, (const float*)nullptr, fc_w1, part1,
                                2048, 8192, b & 15, b >> 4, smem, smem + 256);
  } else if (b < 1040) {
    float (*lil)[128] = (float(*)[128])smem;
    int sb = b - 1024;
    int cb = sb & 1, kc = sb >> 1;          // col chunk (128), k chunk (128)
    for (int i = tid; i < 1536; i += 256) {
      int r = i >> 7, kk = i & 127;
      lil[r][kk] = li[r*1024 + kc*128 + kk];
    }
    __syncthreads();
    int col = cb*128 + (tid & 127);
    int kh = tid >> 7;                      // k-half of 64
    float acc[12];
    #pragma unroll
    for (int t=0;t<12;++t) acc[t]=0.f;
    for (int kk = kh*64; kk < kh*64 + 64; ++kk) {
      float w = gs_w1[(size_t)(kc*128 + kk)*256 + col];
      #pragma unroll
      for (int t=0;t<12;++t) acc[t] = fmaf(lil[t][kk], w, acc[t]);
    }
    int c = kc*2 + kh;                      // 0..15 partial chunk
    #pragma unroll
    for (int t=0;t<12;++t) sp_part[(c*12 + t)*256 + col] = acc[t];
    // zero-duty: outputs 1..3 (36864 floats / 16 blocks)
    for (int i = tid; i < 2304; i += 256) out_tail[sb*2304 + i] = 0.f;
    // init X_raw[2][12288] = fc_b3 (24576 floats / 16 blocks)
    for (int i = tid; i < 1536; i += 256) {
      int idx = sb*1536 + i;
      int colx = idx >= 12288 ? idx - 12288 : idx;
      X_raw[idx] = fc_b3[colx];
    }
  } else {
    float acc = 0.f;
    for (int k = 0; k < 36; ++k)
      acc = fmaf(tf[k], gt_w1[k*256 + tid], acc);
    float v = acc + gt_b1[tid];
    tp_h[tid] = v > 0.f ? v : 0.f;
  }
}

// ---------------------------------------------------------------------------
// k_umid: blocks 0..511 = fc2 GEMM (16 col x 32 k-chunks of 64);
// blocks 512..639 = split-K U-GEMM (4 node-groups x 32 k-chunks of 8),
// partial stores (verified pattern: independent float4 loads, latency
// overlapped with the BW-bound fc2 blocks).
__global__ void __launch_bounds__(256) k_umid(
    const float* __restrict__ part1, const float* __restrict__ fc_b1,
    const float* __restrict__ fc_w2, float* __restrict__ part2,
    const float* __restrict__ sp_part, const float* __restrict__ gs_b1,
    const float* __restrict__ tp_h,
    const float* __restrict__ gs_w2, const float* __restrict__ gt_w2,
    float* __restrict__ U_part, float* __restrict__ tp_part)
{
  __shared__ float smem[2176];  // fc2: lx(128)+red(2048); U: spl(96)+tpl(8)
  int b = blockIdx.x, tid = threadIdx.x;
  if (b < 512) {
    gemm_body<64, 64, 32, 0, 0>(part1, fc_b1, fc_w2, part2, 2048, 2048,
                                b & 15, b >> 4, smem, smem + 128);
    return;
  }
  float* spl = smem;        // 96: relu'd sp hidden [kk<8][t<12]
  float* tpl = smem + 96;   // 8
  int ug = b - 512;
  int n  = (ug & 3)*256 + tid;
  int uy = ug >> 2;
  int k0 = uy*8;
  if (tid < 96) {
    int kk = tid / 12, t = tid % 12;
    float v = gs_b1[k0 + kk];
    #pragma unroll
    for (int c = 0; c < 16; ++c) v += sp_part[(c*12 + t)*256 + k0 + kk];
    spl[kk*12 + t] = v > 0.f ? v : 0.f;
  }
  if (tid < 8) tpl[tid] = tp_h[k0 + tid];
  __syncthreads();
  float sA[3][12];
  float tA[3] = {0.f, 0.f, 0.f};
  #pragma unroll
  for (int ap=0;ap<3;++ap)
    #pragma unroll
    for (int t=0;t<12;++t) sA[ap][t]=0.f;
  #pragma unroll
  for (int kk = 0; kk < 8; ++kk) {
    float4 ws4 = *(const float4*)(gs_w2 + (size_t)(k0+kk)*12288 + 12*n + 8);
    float4 wt4 = *(const float4*)(gt_w2 + (size_t)(k0+kk)*12288 + 12*n + 8);
    float w0 = ws4.y, w1 = ws4.z, w2 = ws4.w;
    #pragma unroll
    for (int t=0;t<12;++t) {
      float s = spl[kk*12 + t];
      sA[0][t] = fmaf(s, w0, sA[0][t]);
      sA[1][t] = fmaf(s, w1, sA[1][t]);
      sA[2][t] = fmaf(s, w2, sA[2][t]);
    }
    float tv = tpl[kk];
    tA[0] = fmaf(tv, wt4.y, tA[0]);
    tA[1] = fmaf(tv, wt4.z, tA[1]);
    tA[2] = fmaf(tv, wt4.w, tA[2]);
  }
  #pragma unroll
  for (int ap=0;ap<3;++ap) {
    #pragma unroll
    for (int t=0;t<12;++t)
      U_part[(size_t)uy*36864 + ap*12288 + n*12 + t] = sA[ap][t];
    tp_part[uy*3072 + n*3 + ap] = tA[ap];
  }
}

// ---------------------------------------------------------------------------
// k_fc3u: blocks 0..1535 = fc3 GEMM (96 col x 16 k-chunks of 128),
// atomicAdd into X_raw (pre-initialized with fc_b3 by k_front);
// blocks 1536..1679 = U finalize (sum 32 partials + bias/relu epilogue).
__global__ void __launch_bounds__(256) k_fc3u(
    const float* __restrict__ part2, const float* __restrict__ fc_b2,
    const float* __restrict__ fc_w3, float* __restrict__ X_raw,
    const float* __restrict__ U_part, const float* __restrict__ tp_part,
    const float* __restrict__ gs_b2, const float* __restrict__ gt_b2,
    float* __restrict__ U)
{
  __shared__ float smem[2304];  // gemm: lx(256)+red(2048)
  int b = blockIdx.x, tid = threadIdx.x;
  if (b < 1536) {
    gemm_body<128, 32, 0, 0, 1>(part2, fc_b2, fc_w3, X_raw, 12288, 2048,
                                b >> 4, b & 15, smem, smem + 256);
    return;
  }
  int i = (b - 1536)*256 + tid;           // < 36864
  float us = 0.f;
  for (int y = 0; y < 32; ++y) us += U_part[(size_t)y*36864 + i];
  int ap = i / 12288, rem = i - ap*12288, n = rem / 12;
  float ts = 0.f;
  for (int y = 0; y < 32; ++y) ts += tp_part[y*3072 + n*3 + ap];
  int c = n*12 + 9 + ap;
  float sv = us + gs_b2[c]; sv = sv > 0.f ? sv : 0.f;
  float tv = ts + gt_b2[c]; tv = tv > 0.f ? tv : 0.f;
  U[i] = sv + tv;
}

// ---------------------------------------------------------------------------
// k_final: fused scores -> threshold -> softmax -> weighted X-sum -> 12x12 Ws
// -> normalize -> epilogue. TWO rows per block; exp values live in LDS only.
// Y folded via linearity: sum_j e_j*(relu(X_j)@Ws) = (sum_j e_j relu(X_j))@Ws;
// relu applied at X_raw point-of-use (bias already inside X_raw).
#define SS 1032
__global__ void __launch_bounds__(256) k_final(
    const float* __restrict__ U, const float* __restrict__ Bm,
    const float* __restrict__ X_raw,
    const float* __restrict__ Wf, const float* __restrict__ Wb,
    const float* __restrict__ bvec, float* __restrict__ out)
{
  __shared__ float sc[6*SS];     // scores/exp; aliased as red after use
  __shared__ float Pm[72];
  __shared__ float invS[6];
  __shared__ float Bl[144];
  __shared__ float Ws0[144], Ws1[144], Ws2[144];
  __shared__ float wbuf[72];
  __shared__ float bl[12];
  int tid = threadIdx.x;
  int i0 = blockIdx.x*2;
  if (tid < 144) {
    Bl[tid]  = Bm[tid];
    Ws0[tid] = Wf[144 + tid];          // Wf[1]       (path 0, L(9,10))
    Ws1[tid] = Wf[tid] + Wb[tid];      // Wf[0]+Wb[0] (path 1, L(10,10))
    Ws2[tid] = Wb[144 + tid];          // Wb[1]       (path 2, L(11,10))
  }
  if (tid < 12) bl[tid] = bvec[tid];
  __syncthreads();
  if (tid < 72) {
    int r = tid / 36, ap = (tid / 12) % 3, j = tid % 12;
    float s = 0.f;
    #pragma unroll
    for (int t=0;t<12;++t)
      s = fmaf(U[ap*12288 + (i0+r)*12 + t], Bl[t*12 + j], s);
    Pm[(r*3+ap)*12 + j] = s;
  }
  __syncthreads();
  const float* U10 = U + 12288;
  for (int jj = 0; jj < 4; ++jj) {
    int j = tid + jj*256;
    const float4* ur = (const float4*)(U10 + j*12);
    float4 u0 = ur[0], u1 = ur[1], u2 = ur[2];
    float u[12] = {u0.x,u0.y,u0.z,u0.w,u1.x,u1.y,u1.z,u1.w,u2.x,u2.y,u2.z,u2.w};
    #pragma unroll
    for (int r=0;r<2;++r)
      #pragma unroll
      for (int ap=0;ap<3;++ap) {
        float s = 0.f;
        #pragma unroll
        for (int t=0;t<12;++t) s = fmaf(Pm[(r*3+ap)*12 + t], u[t], s);
        sc[(r*3+ap)*SS + j] = (s >= 0.05f) ? s : 0.f;
      }
  }
  __syncthreads();
  int wv = tid >> 6, ln = tid & 63;
  for (int pr = wv; pr < 6; pr += 4) {
    float m = -1e30f;
    for (int q = 0; q < 16; ++q) m = fmaxf(m, sc[pr*SS + ln + q*64]);
    #pragma unroll
    for (int o = 32; o > 0; o >>= 1) m = fmaxf(m, __shfl_xor(m, o));
    float sum = 0.f;
    for (int q = 0; q < 16; ++q) {
      int j = ln + q*64;
      float e = __expf(sc[pr*SS + j] - m);
      sc[pr*SS + j] = e;
      sum += e;
    }
    #pragma unroll
    for (int o = 32; o > 0; o >>= 1) sum += __shfl_xor(sum, o);
    if (ln == 0) invS[pr] = 1.f / sum;
  }
  __syncthreads();
  float acc[2][12];
  #pragma unroll
  for (int r = 0; r < 2; ++r)
    #pragma unroll
    for (int f = 0; f < 12; ++f)
      acc[r][f] = 0.f;
  int q3 = tid >> 6, jg = tid & 63;
  if (tid < 192) {
    int row = (q3 == 1) ? 1 : 0;       // paths 0,2 use X9 (row 0); path 1 X10
    const float* xr = X_raw + (size_t)row*12288;
    for (int q = 0; q < 16; ++q) {
      int j = jg + q*64;
      float e0 = sc[q3*SS + j];          // pr = 0*3+q3
      float e1 = sc[(3 + q3)*SS + j];    // pr = 1*3+q3
      const float4* px = (const float4*)(xr + j*12);
      float4 v0 = px[0], v1 = px[1], v2 = px[2];
      float xv[12] = {v0.x,v0.y,v0.z,v0.w,v1.x,v1.y,v1.z,v1.w,v2.x,v2.y,v2.z,v2.w};
      #pragma unroll
      for (int f = 0; f < 12; ++f) {
        float x = xv[f] > 0.f ? xv[f] : 0.f;
        acc[0][f] = fmaf(e0, x, acc[0][f]);
        acc[1][f] = fmaf(e1, x, acc[1][f]);
      }
    }
  }
  __syncthreads();
  float* red = sc;                     // sc values consumed; reuse as scratch
  if (tid < 192) {
    #pragma unroll
    for (int r=0;r<2;++r)
      #pragma unroll
      for (int f=0;f<12;++f)
        red[((q3*2 + r)*12 + f)*64 + jg] = acc[r][f];
  }
  __syncthreads();
  if (tid < 72) {
    int q3b = tid / 24, rr = (tid / 12) % 2, f = tid % 12;
    float s = 0.f;
    for (int g = 0; g < 64; ++g) s += red[((q3b*2 + rr)*12 + f)*64 + g];
    wbuf[(q3b*2 + rr)*12 + f] = s;
  }
  __syncthreads();
  if (tid < 24) {
    int r = tid / 12, g = tid % 12;
    float y0=0.f, y1=0.f, y2=0.f;
    #pragma unroll
    for (int f=0; f<12; ++f) {
      y0 = fmaf(wbuf[(0*2+r)*12+f], Ws0[f*12+g], y0);
      y1 = fmaf(wbuf[(1*2+r)*12+f], Ws1[f*12+g], y1);
      y2 = fmaf(wbuf[(2*2+r)*12+f], Ws2[f*12+g], y2);
    }
    float a1v = invS[r*3+1]*y1;
    float a2v = invS[r*3+0]*y0 + invS[r*3+2]*y2;
    float v1 = a1v + bl[g]; v1 = v1>0.f ? v1 : 0.f;
    float v2 = a2v + bl[g]; v2 = v2>0.f ? v2 : 0.f;
    out[(i0+r)*12 + g] = v1 + v2;
  }
}

extern "C" void kernel_launch(void* const* d_in, const int* in_sizes, int n_in,
                              void* d_out, int out_size, void* d_ws, size_t ws_size,
                              hipStream_t stream)
{
  const float* obs   = (const float*)d_in[0];
  const float* tf    = (const float*)d_in[1];
  const float* fc_w1 = (const float*)d_in[2];
  const float* fc_b1 = (const float*)d_in[3];
  const float* fc_w2 = (const float*)d_in[4];
  const float* fc_b2 = (const float*)d_in[5];
  const float* fc_w3 = (const float*)d_in[6];
  const float* fc_b3 = (const float*)d_in[7];
  const float* Wf    = (const float*)d_in[8];
  const float* Wb    = (const float*)d_in[9];
  const float* bvec  = (const float*)d_in[10];
  const float* li    = (const float*)d_in[11];
  const float* gs_w1 = (const float*)d_in[12];
  const float* gs_b1 = (const float*)d_in[13];
  const float* gs_w2 = (const float*)d_in[14];
  const float* gs_b2 = (const float*)d_in[15];
  const float* gt_w1 = (const float*)d_in[16];
  const float* gt_b1 = (const float*)d_in[17];
  const float* gt_w2 = (const float*)d_in[18];
  const float* gt_b2 = (const float*)d_in[19];
  const float* Bm    = (const float*)d_in[20];
  float* out = (float*)d_out;
  float* ws  = (float*)d_ws;

  float* sp_part = ws + OFF_SPP;
  float* tp_h    = ws + OFF_TPH;
  float* part1   = ws + OFF_P1;
  float* part2   = ws + OFF_P2;
  float* X_raw   = ws + OFF_X;
  float* U_part  = ws + OFF_UP;
  float* tp_part = ws + OFF_TPP;
  float* U       = ws + OFF_U;

  // fc1 (1024, split-K 64x128, obs gathered in staging) + sp/zero/X-init (16)
  // + tp (1)
  k_front<<<dim3(1041), dim3(256), 0, stream>>>(obs, fc_w1, part1,
                                                li, gs_w1, tf, gt_w1, gt_b1,
                                                fc_b3, sp_part, tp_h,
                                                X_raw, out + 12288);
  // fc2 (512, split-K 32x64) || split-K U-GEMM (128) -> U_part, tp_part
  k_umid<<<dim3(640), dim3(256), 0, stream>>>(part1, fc_b1, fc_w2, part2,
                                              sp_part, gs_b1, tp_h,
                                              gs_w2, gt_w2, U_part, tp_part);
  // fc3 (1536, split-K 16x128, atomicAdd into X_raw) || U finalize (144)
  k_fc3u<<<dim3(1680), dim3(256), 0, stream>>>(part2, fc_b2, fc_w3, X_raw,
                                               U_part, tp_part, gs_b2, gt_b2,
                                               U);
  // fused scores/softmax/weighted-sum/epilogue
  k_final<<<dim3(512), dim3(256), 0, stream>>>(U, Bm, X_raw,
                                               Wf, Wb, bvec, out);
}